// Round 4
// baseline (49042.819 us; speedup 1.0000x reference)
//
#include <hip/hip_runtime.h>

#define DI __device__ __forceinline__

constexpr int B_  = 64;
constexpr int T_  = 512;
constexpr int E_  = 256;
constexpr int H_  = 512;
constexpr int G_  = 1536;   // 3*H
constexpr int H2_ = 1024;   // 2*H
constexpr int K_  = 31;
constexpr int BT_ = B_ * T_;
constexpr int TC_ = 64;     // time-chunk length
constexpr int NC_ = T_ / TC_;

typedef float        f32x4  __attribute__((ext_vector_type(4)));
typedef short        bf16x8 __attribute__((ext_vector_type(8)));
typedef unsigned int u32x4  __attribute__((ext_vector_type(4)));

DI float bf2f(unsigned short u) {
    union { unsigned int i; float f; } v; v.i = ((unsigned int)u) << 16; return v.f;
}
DI unsigned short f2bf(float f) {
    union { float f; unsigned int i; } v; v.f = f;
    unsigned int r = v.i + 0x7fffu + ((v.i >> 16) & 1u);
    return (unsigned short)(r >> 16);
}
DI float sigm(float x) { return 1.f / (1.f + __expf(-x)); }
DI float tanh_(float x) {
    x = fminf(15.f, fmaxf(-15.f, x));
    float e = __expf(-2.f * x);
    return (1.f - e) / (1.f + e);
}

#define MFMA16(a, b, c) __builtin_amdgcn_mfma_f32_16x16x32_bf16(a, b, c, 0, 0, 0)

// ---------------- fp32 -> bf16 convert ----------------
__global__ void cvt_f32_bf16(const float* __restrict__ src, unsigned short* __restrict__ dst, int n) {
    int i = blockIdx.x * blockDim.x + threadIdx.x;
    int stride = gridDim.x * blockDim.x;
    for (; i < n; i += stride) dst[i] = f2bf(src[i]);
}

// classifier weight split halves -> bf16, pad row 31 with zeros
__global__ __launch_bounds__(256) void cvt_cls(const float* __restrict__ src,
                                               unsigned short* __restrict__ dstf,
                                               unsigned short* __restrict__ dstb) {
    int i = blockIdx.x * 256 + threadIdx.x;          // [0, 32*512)
    if (i >= 32 * H_) return;
    int n = i >> 9, k = i & 511;
    float vf = (n < K_) ? src[n * H2_ + k] : 0.f;
    float vb = (n < K_) ? src[n * H2_ + H_ + k] : 0.f;
    dstf[i] = f2bf(vf);
    dstb[i] = f2bf(vb);
}

// emissions bias pre-fill (makes later += replay-deterministic)
__global__ __launch_bounds__(256) void emis_bias_init(const float* __restrict__ cls_b,
                                                      float* __restrict__ out1) {
    int i = blockIdx.x * 256 + threadIdx.x;
    int stride = gridDim.x * 256;
    for (; i < BT_ * K_; i += stride) {
        int n = i - (i / K_) * K_;
        out1[i] = cls_b[n];
    }
}

// ---------------- embedding gather (fp32 -> bf16) ----------------
__global__ __launch_bounds__(256) void embed_gather(const int* __restrict__ ids,
                                                    const float* __restrict__ emb,
                                                    unsigned short* __restrict__ xout) {
    int row = blockIdx.x * 4 + (threadIdx.x >> 6);   // [0, BT)
    int l = threadIdx.x & 63;
    int idx = ids[row];
    const float4* src = (const float4*)(emb + (size_t)idx * E_);
    float4 v = src[l];
    unsigned short o[4] = { f2bf(v.x), f2bf(v.y), f2bf(v.z), f2bf(v.w) };
    *(uint2*)(xout + (size_t)row * E_ + l * 4) = *(const uint2*)o;
}

// ---------------- generic bf16 MFMA GEMM ----------------
// C[crow, col] (= or +=) A[arow, :] * W[col, :]^T (+ bias)
// arow = m_base + bx*astride + r ; crow = c_base + bx*cstride + r ; r in [0,64)
template <bool OUTF32, bool ACCUM>
__global__ __launch_bounds__(256) void gemm_bf16(
        const unsigned short* __restrict__ A, int lda, int m_base, int astride,
        const unsigned short* __restrict__ W, int ldw, int nrows,
        const float* __restrict__ bias,
        void* __restrict__ Cout, int ldc, int c_base, int cstride, int nout, int ksz) {
    __shared__ unsigned short As[64][40];   // +8 pad
    __shared__ unsigned short Ws[64][40];
    const int n0 = blockIdx.y * 64;
    const int tid = threadIdx.x;
    const int w = tid >> 6, l = tid & 63;
    const int srow = tid >> 2, sc8 = (tid & 3) * 8;
    const int mw = (w >> 1) * 32, nw = (w & 1) * 32;
    const int fl = l & 15, fk = (l >> 4) * 8;
    const size_t arow0 = (size_t)m_base + (size_t)blockIdx.x * astride;
    f32x4 zero4 = { 0.f, 0.f, 0.f, 0.f };
    f32x4 acc[2][2];
    acc[0][0] = zero4; acc[0][1] = zero4; acc[1][0] = zero4; acc[1][1] = zero4;

    for (int kc = 0; kc < ksz; kc += 32) {
        u32x4 av = *(const u32x4*)(A + (arow0 + srow) * lda + kc + sc8);
        u32x4 wv;
        if (n0 + srow < nrows) wv = *(const u32x4*)(W + (size_t)(n0 + srow) * ldw + kc + sc8);
        else { u32x4 z = { 0u, 0u, 0u, 0u }; wv = z; }
        __syncthreads();
        *(u32x4*)&As[srow][sc8] = av;
        *(u32x4*)&Ws[srow][sc8] = wv;
        __syncthreads();
        bf16x8 a0 = *(const bf16x8*)&As[mw + fl][fk];
        bf16x8 a1 = *(const bf16x8*)&As[mw + 16 + fl][fk];
        bf16x8 b0 = *(const bf16x8*)&Ws[nw + fl][fk];
        bf16x8 b1 = *(const bf16x8*)&Ws[nw + 16 + fl][fk];
        acc[0][0] = MFMA16(a0, b0, acc[0][0]);
        acc[0][1] = MFMA16(a0, b1, acc[0][1]);
        acc[1][0] = MFMA16(a1, b0, acc[1][0]);
        acc[1][1] = MFMA16(a1, b1, acc[1][1]);
    }

    #pragma unroll
    for (int mf = 0; mf < 2; ++mf)
        #pragma unroll
        for (int nf = 0; nf < 2; ++nf) {
            int col = n0 + nw + nf * 16 + fl;
            if (col >= nout) continue;
            float bv = bias ? bias[col] : 0.f;
            #pragma unroll
            for (int j = 0; j < 4; ++j) {
                int r = mw + mf * 16 + (l >> 4) * 4 + j;
                size_t crow = (size_t)c_base + (size_t)blockIdx.x * cstride + r;
                float v = acc[mf][nf][j] + bv;
                if (OUTF32) {
                    float* C = (float*)Cout;
                    if (ACCUM) C[crow * ldc + col] += v;
                    else       C[crow * ldc + col] = v;
                } else {
                    ((unsigned short*)Cout)[crow * ldc + col] = f2bf(v);
                }
            }
        }
}

// ---------------- persistent GRU scan over one time-chunk ----------------
// grid(256): bid%8 selects XCD (round-robin heuristic). Workers: bid%8==0 ->
// dir 0 (XCD0), bid%8==4 -> dir 1 (XCD4); worker = bid>>3 in [0,32). Others
// exit. Correctness never depends on placement (agent-scope fences+flags);
// placement only shortens the h/flag round trip to XCD-local L2.
// Barrier: per-block flag (128B-padded), release-store arrival, wave-0
// parallel poll of 32 flags. Flags zeroed once per kernel_launch; monotone
// targets -> replay-deterministic.
__global__ __launch_bounds__(256) void gru_scan(int c,
        const unsigned short* __restrict__ xpc_f, const unsigned short* __restrict__ xpc_b,
        const unsigned short* __restrict__ whh_f, const unsigned short* __restrict__ whh_b,
        const float* __restrict__ bhh_f, const float* __restrict__ bhh_b,
        unsigned short* __restrict__ hbf,   // [parity][dir][B][H] bf16
        float* __restrict__ hfp,            // [parity][dir][B][H] f32
        unsigned short* __restrict__ out_f, unsigned short* __restrict__ out_b,
        int ldo, int mode, int* __restrict__ flags2) {
    __shared__ unsigned short wsl[48 * 512];        // 48KB, XOR-swizzled
    const int bid = blockIdx.x;
    const int xcd = bid & 7;
    int dir;
    if (xcd == 0) dir = 0;
    else if (xcd == 4) dir = 1;
    else return;
    const int worker = bid >> 3;                    // [0, 32)
    const int u0 = worker * 16;
    const int tid = threadIdx.x;
    const int w = tid >> 6, l = tid & 63;
    const int fl = l & 15, fko = (l >> 4) * 8;
    const unsigned short* xp  = dir ? xpc_b : xpc_f;
    const unsigned short* whh = dir ? whh_b : whh_f;
    const float* bhh = dir ? bhh_b : bhh_f;
    unsigned short* outp = dir ? out_b : out_f;
    int* pollbase = flags2 + dir * 1024;            // 32 flags, stride 32 ints
    int* myflag   = pollbase + worker * 32;
    const int dofs = dir * (B_ * H_);
    const int PHB = 2 * B_ * H_;

    // stage 48 gate rows (gate g, units u0..u0+15) into swizzled LDS -- once
    #pragma unroll
    for (int it = 0; it < 12; ++it) {
        int cidx = it * 256 + tid;           // [0, 3072)
        int lr  = cidx >> 6;                 // local row [0,48)
        int kc8 = (cidx & 63) << 3;          // k offset, step 8
        int g = lr >> 4, cc = lr & 15;
        int grow = g * H_ + u0 + cc;         // global gate row
        u32x4 v = *(const u32x4*)(whh + (size_t)grow * H_ + kc8);
        unsigned int byt = (unsigned int)(lr * 1024 + (kc8 << 1));
        byt ^= ((unsigned int)(lr & 7)) << 4;
        *(u32x4*)((char*)wsl + byt) = v;
    }
    __syncthreads();

    const int u = u0 + fl;
    const float br_ = bhh[u], bz_ = bhh[H_ + u], bn_ = bhh[2 * H_ + u];
    const int mrow = w * 16 + ((l >> 4) << 2);   // batch base for epilogue

    unsigned short xg[3][4];
    auto ldxp = [&](int tl) {
        #pragma unroll
        for (int j = 0; j < 4; ++j) {
            const unsigned short* xb = xp + ((size_t)(mrow + j) * TC_ + tl) * G_ + u;
            xg[0][j] = xb[0]; xg[1][j] = xb[H_]; xg[2][j] = xb[2 * H_];
        }
    };
    ldxp(dir ? (TC_ - 1) : 0);

    for (int sl = 0; sl < TC_; ++sl) {
        const int s = c * TC_ + sl;
        const int t = dir ? (T_ - 1 - s) : s;
        const int tloc = dir ? (TC_ - 1 - sl) : sl;

        f32x4 zero4 = { 0.f, 0.f, 0.f, 0.f };
        f32x4 acc[3];
        acc[0] = zero4; acc[1] = zero4; acc[2] = zero4;

        if (s > 0) {
            const unsigned short* ap = hbf + (((s & 1) ^ 1) * PHB) + dofs
                                     + (size_t)(w * 16 + fl) * H_ + fko;
            bf16x8 af[16];
            #pragma unroll
            for (int ks = 0; ks < 16; ++ks) af[ks] = *(const bf16x8*)(ap + ks * 32);
            #pragma unroll
            for (int ks = 0; ks < 16; ++ks) {
                bf16x8 bfr[3];
                #pragma unroll
                for (int g = 0; g < 3; ++g) {
                    int lr = g * 16 + fl;
                    unsigned int byt = (unsigned int)(lr * 1024 + ((ks * 32 + fko) << 1));
                    byt ^= ((unsigned int)(lr & 7)) << 4;
                    bfr[g] = *(const bf16x8*)((const char*)wsl + byt);
                }
                #pragma unroll
                for (int g = 0; g < 3; ++g) acc[g] = MFMA16(af[ks], bfr[g], acc[g]);
            }
        }

        const float* frd = hfp + (((s & 1) ^ 1) * PHB) + dofs;
        float*       fwr = hfp + ((s & 1) * PHB) + dofs;
        unsigned short* hwr = hbf + ((s & 1) * PHB) + dofs;
        #pragma unroll
        for (int j = 0; j < 4; ++j) {
            int m = mrow + j;
            float xr = bf2f(xg[0][j]);
            float xz = bf2f(xg[1][j]);
            float xn = bf2f(xg[2][j]);
            float r = sigm(xr + acc[0][j] + br_);
            float z = sigm(xz + acc[1][j] + bz_);
            float nn = tanh_(xn + r * (acc[2][j] + bn_));
            float hp = (s > 0) ? frd[m * H_ + u] : 0.f;
            float hv = (1.f - z) * nn + z * hp;
            fwr[m * H_ + u] = hv;
            hwr[m * H_ + u] = f2bf(hv);
            size_t row = mode ? (size_t)(m * TC_ + tloc) : ((size_t)m * T_ + t);
            outp[row * ldo + u] = f2bf(hv);
        }

        if (sl < TC_ - 1) {
            __threadfence();                 // flush h stores toward coherence point
            __syncthreads();                 // whole block done (drains vmcnt)
            if (tid == 0)
                __hip_atomic_store(myflag, sl + 1, __ATOMIC_RELEASE, __HIP_MEMORY_SCOPE_AGENT);
            ldxp(dir ? (TC_ - 2 - sl) : (sl + 1));   // prefetch next xp during wait
            if (w == 0) {
                const int need = sl + 1;
                int v = need;
                if (l < 32)
                    v = __hip_atomic_load(pollbase + l * 32, __ATOMIC_RELAXED, __HIP_MEMORY_SCOPE_AGENT);
                while (!__all(v >= need)) {
                    __builtin_amdgcn_s_sleep(1);
                    if (l < 32)
                        v = __hip_atomic_load(pollbase + l * 32, __ATOMIC_RELAXED, __HIP_MEMORY_SCOPE_AGENT);
                }
            }
            __syncthreads();
            __threadfence();                 // acquire: invalidate stale h before reads
        }
    }
}

// ---------------- CRF: one block per batch element ----------------
__global__ __launch_bounds__(64) void crf_kernel(const float* __restrict__ em,     // [BT][K]
                                                 const int* __restrict__ labels,
                                                 const float* __restrict__ start,
                                                 const float* __restrict__ endv,
                                                 const float* __restrict__ trans,
                                                 float* __restrict__ partials) {
    __shared__ float tr[31 * 32];
    __shared__ float al[32];
    const int b = blockIdx.x, l = threadIdx.x;
    for (int e2 = l; e2 < 961; e2 += 64) {
        int r = e2 / 31, c = e2 - r * 31;
        tr[r * 32 + c] = trans[e2];
    }
    __syncthreads();
    const int* lab = labels + b * T_;
    const float* eb = em + (size_t)b * T_ * K_;

    float part = 0.f, cnt = 0.f;
    for (int t = l; t < T_; t += 64) {
        int lt = lab[t];
        if (lt > -1) {
            cnt += 1.f;
            if (t > 0) part += tr[lab[t - 1] * 32 + lt] + eb[t * K_ + lt];
        }
    }
    #pragma unroll
    for (int o = 32; o; o >>= 1) { part += __shfl_xor(part, o); cnt += __shfl_xor(cnt, o); }
    int lastidx = (int)cnt - 1;
    float num = part + start[lab[0]] + eb[lab[0]] + endv[lab[lastidx]];

    float a = (l < K_) ? (start[l] + eb[l]) : -3.0e38f;
    for (int t = 1; t < T_; ++t) {
        if (l < K_) al[l] = a;
        __syncthreads();
        if (l < K_) {
            float m = -3.0e38f;
            #pragma unroll
            for (int i = 0; i < K_; ++i) m = fmaxf(m, al[i] + tr[i * 32 + l]);
            float ss = 0.f;
            #pragma unroll
            for (int i = 0; i < K_; ++i) ss += __expf(al[i] + tr[i * 32 + l] - m);
            float anew = eb[t * K_ + l] + m + __logf(ss);
            if (lab[t] > -1) a = anew;
        }
        __syncthreads();
    }
    float v = (l < K_) ? (a + endv[l]) : -3.0e38f;
    float m = v;
    #pragma unroll
    for (int o = 32; o; o >>= 1) m = fmaxf(m, __shfl_xor(m, o));
    float ss = (l < K_) ? __expf(v - m) : 0.f;
    #pragma unroll
    for (int o = 32; o; o >>= 1) ss += __shfl_xor(ss, o);
    if (l == 0) partials[b] = num - (m + __logf(ss));
}

__global__ __launch_bounds__(64) void loss_reduce(const float* __restrict__ partials,
                                                  float* __restrict__ out) {
    float v = partials[threadIdx.x];
    #pragma unroll
    for (int o = 32; o; o >>= 1) v += __shfl_xor(v, o);
    if (threadIdx.x == 0) out[0] = -v;
}

__global__ void sentinel(float* __restrict__ out, float v) { out[0] = -v; }

// ---------------- host ----------------
extern "C" void kernel_launch(void* const* d_in, const int* in_sizes, int n_in,
                              void* d_out, int out_size, void* d_ws, size_t ws_size,
                              hipStream_t stream) {
    const int*   ids      = (const int*)d_in[0];
    const int*   labels   = (const int*)d_in[1];
    const float* emb      = (const float*)d_in[2];
    const float* wih[4]   = { (const float*)d_in[3], (const float*)d_in[7], (const float*)d_in[11], (const float*)d_in[15] };
    const float* whh[4]   = { (const float*)d_in[4], (const float*)d_in[8], (const float*)d_in[12], (const float*)d_in[16] };
    const float* bih[4]   = { (const float*)d_in[5], (const float*)d_in[9], (const float*)d_in[13], (const float*)d_in[17] };
    const float* bhh[4]   = { (const float*)d_in[6], (const float*)d_in[10], (const float*)d_in[14], (const float*)d_in[18] };
    const float* cls_w    = (const float*)d_in[19];
    const float* cls_b    = (const float*)d_in[20];
    const float* c_start  = (const float*)d_in[21];
    const float* c_end    = (const float*)d_in[22];
    const float* c_trans  = (const float*)d_in[23];
    float* out = (float*)d_out;
    float* out1 = out + 1;

    char* p = (char*)d_ws;
    size_t used = 0;
    auto alloc = [&](size_t bytes) -> char* {
        char* r = p;
        size_t a = (bytes + 255) & ~(size_t)255;
        p += a; used += a;
        return r;
    };
    unsigned short* xpcf = (unsigned short*)alloc((size_t)B_ * TC_ * G_ * 2);   // 12.6MB
    unsigned short* xpcb = (unsigned short*)alloc((size_t)B_ * TC_ * G_ * 2);   // 12.6MB
    unsigned short* h1   = (unsigned short*)alloc((size_t)BT_ * H2_ * 2);       // 67MB
    unsigned short* xbf  = (unsigned short*)alloc((size_t)BT_ * E_ * 2);        // 16.8MB
    // layer-1 output chunks alias the (then-dead) embedding buffer
    unsigned short* gof  = xbf;
    unsigned short* gob  = xbf + (size_t)B_ * TC_ * H_;
    unsigned short* wihb[4];
    unsigned short* whhb[4];
    const int wihsz[4] = { G_ * E_, G_ * E_, G_ * H2_, G_ * H2_ };
    for (int i = 0; i < 4; ++i) {
        wihb[i] = (unsigned short*)alloc((size_t)wihsz[i] * 2);
        whhb[i] = (unsigned short*)alloc((size_t)G_ * H_ * 2);
    }
    unsigned short* clsf  = (unsigned short*)alloc((size_t)32 * H_ * 2);
    unsigned short* clshb = (unsigned short*)alloc((size_t)32 * H_ * 2);
    unsigned short* hbf   = (unsigned short*)alloc((size_t)2 * 2 * B_ * H_ * 2);  // [parity][dir][B][H]
    float*          hfp   = (float*)alloc((size_t)2 * 2 * B_ * H_ * 4);
    float*          partials = (float*)alloc((size_t)B_ * 4);
    int*            flags = (int*)alloc((size_t)2 * NC_ * 2048 * 4);            // [launch][dir*1024 + wk*32]

    if (used > ws_size) {
        sentinel<<<dim3(1), dim3(1), 0, stream>>>(out, (float)(ws_size >> 20));
        return;
    }

    hipMemsetAsync(flags, 0, (size_t)2 * NC_ * 2048 * 4, stream);

    auto cvt = [&](const float* s_, unsigned short* d_, int n) {
        int grid = (n + 255) / 256; if (grid > 2048) grid = 2048;
        cvt_f32_bf16<<<dim3(grid), dim3(256), 0, stream>>>(s_, d_, n);
    };
    for (int i = 0; i < 4; ++i) { cvt(wih[i], wihb[i], wihsz[i]); cvt(whh[i], whhb[i], G_ * H_); }
    cvt_cls<<<dim3((32 * H_ + 255) / 256), dim3(256), 0, stream>>>(cls_w, clsf, clshb);
    emis_bias_init<<<dim3(1024), dim3(256), 0, stream>>>(cls_b, out1);
    embed_gather<<<dim3(BT_ / 4), dim3(256), 0, stream>>>(ids, emb, xbf);

    for (int layer = 0; layer < 2; ++layer) {
        const unsigned short* Ain = layer ? h1 : xbf;
        const int lda  = layer ? H2_ : E_;
        const unsigned short* wf = wihb[layer * 2 + 0];
        const unsigned short* wb = wihb[layer * 2 + 1];
        const float* bf_ = bih[layer * 2 + 0];
        const float* bb_ = bih[layer * 2 + 1];
        const unsigned short* whf = whhb[layer * 2 + 0];
        const unsigned short* whb = whhb[layer * 2 + 1];
        const float* bhf = bhh[layer * 2 + 0];
        const float* bhb = bhh[layer * 2 + 1];

        for (int c = 0; c < NC_; ++c) {
            int t0f = c * TC_;
            int t0b = T_ - (c + 1) * TC_;
            // xp for this chunk (bias folded, bf16 out)
            gemm_bf16<false, false><<<dim3(B_, G_ / 64), dim3(256), 0, stream>>>(
                Ain, lda, t0f, T_, wf, lda, G_, bf_, (void*)xpcf, G_, 0, TC_, G_, lda);
            gemm_bf16<false, false><<<dim3(B_, G_ / 64), dim3(256), 0, stream>>>(
                Ain, lda, t0b, T_, wb, lda, G_, bb_, (void*)xpcb, G_, 0, TC_, G_, lda);
            // persistent scan over the chunk (XCD-affinity grid of 256)
            int* fl2 = flags + (layer * NC_ + c) * 2048;
            if (layer == 0) {
                gru_scan<<<dim3(256), dim3(256), 0, stream>>>(c, xpcf, xpcb,
                    whf, whb, bhf, bhb, hbf, hfp, h1, h1 + H_, H2_, 0, fl2);
            } else {
                gru_scan<<<dim3(256), dim3(256), 0, stream>>>(c, xpcf, xpcb,
                    whf, whb, bhf, bhb, hbf, hfp, gof, gob, H_, 1, fl2);
            }
            if (layer == 1) {
                // split-K emissions for the fresh rows of this chunk (+= into out1)
                gemm_bf16<true, true><<<dim3(B_, 1), dim3(256), 0, stream>>>(
                    gof, H_, 0, TC_, clsf, H_, 32, nullptr, (void*)out1, K_, t0f, T_, K_, H_);
                gemm_bf16<true, true><<<dim3(B_, 1), dim3(256), 0, stream>>>(
                    gob, H_, 0, TC_, clshb, H_, 32, nullptr, (void*)out1, K_, t0b, T_, K_, H_);
            }
        }
    }

    crf_kernel<<<dim3(B_), dim3(64), 0, stream>>>(out1, labels, c_start, c_end, c_trans, partials);
    loss_reduce<<<dim3(1), dim3(64), 0, stream>>>(partials, out);
}

// Round 5
// 7570.668 us; speedup vs baseline: 6.4780x; 6.4780x over previous
//
#include <hip/hip_runtime.h>

#define DI __device__ __forceinline__

constexpr int B_  = 64;
constexpr int T_  = 512;
constexpr int E_  = 256;
constexpr int H_  = 512;
constexpr int G_  = 1536;   // 3*H
constexpr int H2_ = 1024;   // 2*H
constexpr int K_  = 31;
constexpr int BT_ = B_ * T_;
constexpr int TC_ = 64;     // time-chunk length
constexpr int NC_ = T_ / TC_;

typedef float        f32x4  __attribute__((ext_vector_type(4)));
typedef short        bf16x8 __attribute__((ext_vector_type(8)));
typedef unsigned int u32x4  __attribute__((ext_vector_type(4)));

DI float bf2f(unsigned short u) {
    union { unsigned int i; float f; } v; v.i = ((unsigned int)u) << 16; return v.f;
}
DI unsigned short f2bf(float f) {
    union { float f; unsigned int i; } v; v.f = f;
    unsigned int r = v.i + 0x7fffu + ((v.i >> 16) & 1u);
    return (unsigned short)(r >> 16);
}
DI float sigm(float x) { return 1.f / (1.f + __expf(-x)); }
DI float tanh_(float x) {
    x = fminf(15.f, fmaxf(-15.f, x));
    float e = __expf(-2.f * x);
    return (1.f - e) / (1.f + e);
}

#define MFMA16(a, b, c) __builtin_amdgcn_mfma_f32_16x16x32_bf16(a, b, c, 0, 0, 0)

// ---------------- fp32 -> bf16 convert ----------------
__global__ void cvt_f32_bf16(const float* __restrict__ src, unsigned short* __restrict__ dst, int n) {
    int i = blockIdx.x * blockDim.x + threadIdx.x;
    int stride = gridDim.x * blockDim.x;
    for (; i < n; i += stride) dst[i] = f2bf(src[i]);
}

// classifier weight split halves -> bf16, pad row 31 with zeros
__global__ __launch_bounds__(256) void cvt_cls(const float* __restrict__ src,
                                               unsigned short* __restrict__ dstf,
                                               unsigned short* __restrict__ dstb) {
    int i = blockIdx.x * 256 + threadIdx.x;          // [0, 32*512)
    if (i >= 32 * H_) return;
    int n = i >> 9, k = i & 511;
    float vf = (n < K_) ? src[n * H2_ + k] : 0.f;
    float vb = (n < K_) ? src[n * H2_ + H_ + k] : 0.f;
    dstf[i] = f2bf(vf);
    dstb[i] = f2bf(vb);
}

// emissions bias pre-fill (makes later += replay-deterministic)
__global__ __launch_bounds__(256) void emis_bias_init(const float* __restrict__ cls_b,
                                                      float* __restrict__ out1) {
    int i = blockIdx.x * 256 + threadIdx.x;
    int stride = gridDim.x * 256;
    for (; i < BT_ * K_; i += stride) {
        int n = i - (i / K_) * K_;
        out1[i] = cls_b[n];
    }
}

// ---------------- embedding gather (fp32 -> bf16) ----------------
__global__ __launch_bounds__(256) void embed_gather(const int* __restrict__ ids,
                                                    const float* __restrict__ emb,
                                                    unsigned short* __restrict__ xout) {
    int row = blockIdx.x * 4 + (threadIdx.x >> 6);   // [0, BT)
    int l = threadIdx.x & 63;
    int idx = ids[row];
    const float4* src = (const float4*)(emb + (size_t)idx * E_);
    float4 v = src[l];
    unsigned short o[4] = { f2bf(v.x), f2bf(v.y), f2bf(v.z), f2bf(v.w) };
    *(uint2*)(xout + (size_t)row * E_ + l * 4) = *(const uint2*)o;
}

// ---------------- generic bf16 MFMA GEMM ----------------
// C[crow, col] (= or +=) A[arow, :] * W[col, :]^T (+ bias)
// arow = m_base + bx*astride + r ; crow = c_base + bx*cstride + r ; r in [0,64)
template <bool OUTF32, bool ACCUM>
__global__ __launch_bounds__(256) void gemm_bf16(
        const unsigned short* __restrict__ A, int lda, int m_base, int astride,
        const unsigned short* __restrict__ W, int ldw, int nrows,
        const float* __restrict__ bias,
        void* __restrict__ Cout, int ldc, int c_base, int cstride, int nout, int ksz) {
    __shared__ unsigned short As[64][40];   // +8 pad
    __shared__ unsigned short Ws[64][40];
    const int n0 = blockIdx.y * 64;
    const int tid = threadIdx.x;
    const int w = tid >> 6, l = tid & 63;
    const int srow = tid >> 2, sc8 = (tid & 3) * 8;
    const int mw = (w >> 1) * 32, nw = (w & 1) * 32;
    const int fl = l & 15, fk = (l >> 4) * 8;
    const size_t arow0 = (size_t)m_base + (size_t)blockIdx.x * astride;
    f32x4 zero4 = { 0.f, 0.f, 0.f, 0.f };
    f32x4 acc[2][2];
    acc[0][0] = zero4; acc[0][1] = zero4; acc[1][0] = zero4; acc[1][1] = zero4;

    for (int kc = 0; kc < ksz; kc += 32) {
        u32x4 av = *(const u32x4*)(A + (arow0 + srow) * lda + kc + sc8);
        u32x4 wv;
        if (n0 + srow < nrows) wv = *(const u32x4*)(W + (size_t)(n0 + srow) * ldw + kc + sc8);
        else { u32x4 z = { 0u, 0u, 0u, 0u }; wv = z; }
        __syncthreads();
        *(u32x4*)&As[srow][sc8] = av;
        *(u32x4*)&Ws[srow][sc8] = wv;
        __syncthreads();
        bf16x8 a0 = *(const bf16x8*)&As[mw + fl][fk];
        bf16x8 a1 = *(const bf16x8*)&As[mw + 16 + fl][fk];
        bf16x8 b0 = *(const bf16x8*)&Ws[nw + fl][fk];
        bf16x8 b1 = *(const bf16x8*)&Ws[nw + 16 + fl][fk];
        acc[0][0] = MFMA16(a0, b0, acc[0][0]);
        acc[0][1] = MFMA16(a0, b1, acc[0][1]);
        acc[1][0] = MFMA16(a1, b0, acc[1][0]);
        acc[1][1] = MFMA16(a1, b1, acc[1][1]);
    }

    #pragma unroll
    for (int mf = 0; mf < 2; ++mf)
        #pragma unroll
        for (int nf = 0; nf < 2; ++nf) {
            int col = n0 + nw + nf * 16 + fl;
            if (col >= nout) continue;
            float bv = bias ? bias[col] : 0.f;
            #pragma unroll
            for (int j = 0; j < 4; ++j) {
                int r = mw + mf * 16 + (l >> 4) * 4 + j;
                size_t crow = (size_t)c_base + (size_t)blockIdx.x * cstride + r;
                float v = acc[mf][nf][j] + bv;
                if (OUTF32) {
                    float* C = (float*)Cout;
                    if (ACCUM) C[crow * ldc + col] += v;
                    else       C[crow * ldc + col] = v;
                } else {
                    ((unsigned short*)Cout)[crow * ldc + col] = f2bf(v);
                }
            }
        }
}

// ---------------- persistent GRU scan over one time-chunk ----------------
// grid(64): bid>>5 = dir, bid&31 = unit-block (16 units). Weights LDS-resident
// for the whole chunk. NO threadfence anywhere: all cross-block h exchange is
// relaxed agent-scope atomics on hpub (u32 = 2 packed bf16 units), which
// execute at the coherence point. fp32 recurrent state lives in registers
// (hcar carries it across chunk launches). Barrier: per-block padded flag,
// relaxed store after __syncthreads (which drains vmcnt, i.e. h stores are
// acked at the coherence point), wave-0 parallel poll. Monotone targets,
// flags zeroed per launch -> replay-deterministic.
__global__ __launch_bounds__(256) void gru_scan(int c,
        const unsigned short* __restrict__ xpc_f, const unsigned short* __restrict__ xpc_b,
        const unsigned short* __restrict__ whh_f, const unsigned short* __restrict__ whh_b,
        const float* __restrict__ bhh_f, const float* __restrict__ bhh_b,
        unsigned int* __restrict__ hpub,    // [dir][parity][B][H/2] u32
        float* __restrict__ hcar,           // [dir][B][H] f32 chunk-carry
        unsigned short* __restrict__ out_f, unsigned short* __restrict__ out_b,
        int ldo, int mode, int* __restrict__ flags2) {
    __shared__ unsigned short wsl[48 * 512];        // 48KB, XOR-swizzled
    const int bid = blockIdx.x;
    const int dir = bid >> 5;
    const int worker = bid & 31;
    const int u0 = worker * 16;
    const int tid = threadIdx.x;
    const int w = tid >> 6, l = tid & 63;
    const int fl = l & 15, fko = (l >> 4) * 8;
    const unsigned short* xp  = dir ? xpc_b : xpc_f;
    const unsigned short* whh = dir ? whh_b : whh_f;
    const float* bhh = dir ? bhh_b : bhh_f;
    unsigned short* outp = dir ? out_b : out_f;
    int* pollbase = flags2 + dir * 1024;            // 32 flags, stride 32 ints
    int* myflag   = pollbase + worker * 32;

    // stage 48 gate rows (gate g, units u0..u0+15) into swizzled LDS -- once per chunk
    #pragma unroll
    for (int it = 0; it < 12; ++it) {
        int cidx = it * 256 + tid;           // [0, 3072)
        int lr  = cidx >> 6;                 // local row [0,48)
        int kc8 = (cidx & 63) << 3;          // k offset, step 8
        int g = lr >> 4, cc = lr & 15;
        int grow = g * H_ + u0 + cc;         // global gate row
        u32x4 v = *(const u32x4*)(whh + (size_t)grow * H_ + kc8);
        unsigned int byt = (unsigned int)(lr * 1024 + (kc8 << 1));
        byt ^= ((unsigned int)(lr & 7)) << 4;
        *(u32x4*)((char*)wsl + byt) = v;
    }
    __syncthreads();

    const int u = u0 + fl;
    const float br_ = bhh[u], bz_ = bhh[H_ + u], bn_ = bhh[2 * H_ + u];
    const int mrow = w * 16 + ((l >> 4) << 2);   // batch base for epilogue

    // fp32 recurrent state in registers (chunk-carried)
    float hp[4];
    if (c > 0) {
        #pragma unroll
        for (int j = 0; j < 4; ++j) hp[j] = hcar[dir * (B_ * H_) + (mrow + j) * H_ + u];
    } else {
        #pragma unroll
        for (int j = 0; j < 4; ++j) hp[j] = 0.f;
    }

    unsigned short xg[3][4];
    auto ldxp = [&](int tl) {
        #pragma unroll
        for (int j = 0; j < 4; ++j) {
            const unsigned short* xb = xp + ((size_t)(mrow + j) * TC_ + tl) * G_ + u;
            xg[0][j] = xb[0]; xg[1][j] = xb[H_]; xg[2][j] = xb[2 * H_];
        }
    };
    ldxp(dir ? (TC_ - 1) : 0);

    for (int sl = 0; sl < TC_; ++sl) {
        const int s = c * TC_ + sl;
        const int t = dir ? (T_ - 1 - s) : s;
        const int tloc = dir ? (TC_ - 1 - sl) : sl;

        f32x4 zero4 = { 0.f, 0.f, 0.f, 0.f };
        f32x4 acc[3];
        acc[0] = zero4; acc[1] = zero4; acc[2] = zero4;

        if (s > 0) {
            // A fragments: previous h, parity (s-1)&1, via coherence-point loads.
            // u64 load = 4 packed bf16 (2 u32 of 2 units each) -> half a frag.
            const unsigned int* hb = hpub
                + ((size_t)(dir * 2 + ((s & 1) ^ 1)) * B_ + (w * 16 + fl)) * (H_ / 2)
                + (fko >> 1);
            unsigned long long raw[32];
            #pragma unroll
            for (int ks = 0; ks < 16; ++ks) {
                raw[2 * ks]     = __hip_atomic_load((const unsigned long long*)(hb + ks * 16),
                                      __ATOMIC_RELAXED, __HIP_MEMORY_SCOPE_AGENT);
                raw[2 * ks + 1] = __hip_atomic_load((const unsigned long long*)(hb + ks * 16 + 2),
                                      __ATOMIC_RELAXED, __HIP_MEMORY_SCOPE_AGENT);
            }
            #pragma unroll
            for (int ks = 0; ks < 16; ++ks) {
                union { unsigned long long q[2]; bf16x8 v; } uu;
                uu.q[0] = raw[2 * ks]; uu.q[1] = raw[2 * ks + 1];
                bf16x8 afr = uu.v;
                bf16x8 bfr[3];
                #pragma unroll
                for (int g = 0; g < 3; ++g) {
                    int lr = g * 16 + fl;
                    unsigned int byt = (unsigned int)(lr * 1024 + ((ks * 32 + fko) << 1));
                    byt ^= ((unsigned int)(lr & 7)) << 4;
                    bfr[g] = *(const bf16x8*)((const char*)wsl + byt);
                }
                #pragma unroll
                for (int g = 0; g < 3; ++g) acc[g] = MFMA16(afr, bfr[g], acc[g]);
            }
        }

        // epilogue: lane-local r,z,n for unit u; batches mrow..mrow+3
        unsigned int* hw = hpub + ((size_t)(dir * 2 + (s & 1)) * B_) * (H_ / 2);
        #pragma unroll
        for (int j = 0; j < 4; ++j) {
            int m = mrow + j;
            float xr = bf2f(xg[0][j]);
            float xz = bf2f(xg[1][j]);
            float xn = bf2f(xg[2][j]);
            float r = sigm(xr + acc[0][j] + br_);
            float z = sigm(xz + acc[1][j] + bz_);
            float nn = tanh_(xn + r * (acc[2][j] + bn_));
            float hv = (1.f - z) * nn + z * hp[j];
            hp[j] = hv;
            unsigned short hb16 = f2bf(hv);
            size_t row = mode ? (size_t)(m * TC_ + tloc) : ((size_t)m * T_ + t);
            outp[row * ldo + u] = hb16;
            // pack 2 adjacent units (lane ^ 1) into one u32; even-unit lanes store
            int pv = __shfl_xor((int)hb16, 1);
            if ((fl & 1) == 0) {
                unsigned int pk = (unsigned int)hb16 | ((unsigned int)pv << 16);
                __hip_atomic_store(hw + (size_t)m * (H_ / 2) + (u >> 1), pk,
                                   __ATOMIC_RELAXED, __HIP_MEMORY_SCOPE_AGENT);
            }
        }

        if (sl < TC_ - 1) {
            asm volatile("s_waitcnt vmcnt(0)" ::: "memory");  // h stores acked at coherence point
            __syncthreads();                                  // whole block done
            if (tid == 0)
                __hip_atomic_store(myflag, sl + 1, __ATOMIC_RELAXED, __HIP_MEMORY_SCOPE_AGENT);
            ldxp(dir ? (TC_ - 2 - sl) : (sl + 1));            // prefetch next xp during wait
            if (w == 0) {
                const int need = sl + 1;
                int v = need;
                if (l < 32)
                    v = __hip_atomic_load(pollbase + l * 32, __ATOMIC_RELAXED, __HIP_MEMORY_SCOPE_AGENT);
                while (!__all(v >= need)) {
                    __builtin_amdgcn_s_sleep(2);
                    if (l < 32)
                        v = __hip_atomic_load(pollbase + l * 32, __ATOMIC_RELAXED, __HIP_MEMORY_SCOPE_AGENT);
                }
            }
            __syncthreads();
        }
    }

    // carry fp32 state to next chunk
    #pragma unroll
    for (int j = 0; j < 4; ++j) hcar[dir * (B_ * H_) + (mrow + j) * H_ + u] = hp[j];
}

// ---------------- CRF: one block per batch element ----------------
__global__ __launch_bounds__(64) void crf_kernel(const float* __restrict__ em,     // [BT][K]
                                                 const int* __restrict__ labels,
                                                 const float* __restrict__ start,
                                                 const float* __restrict__ endv,
                                                 const float* __restrict__ trans,
                                                 float* __restrict__ partials) {
    __shared__ float tr[31 * 32];
    __shared__ float al[32];
    const int b = blockIdx.x, l = threadIdx.x;
    for (int e2 = l; e2 < 961; e2 += 64) {
        int r = e2 / 31, c = e2 - r * 31;
        tr[r * 32 + c] = trans[e2];
    }
    __syncthreads();
    const int* lab = labels + b * T_;
    const float* eb = em + (size_t)b * T_ * K_;

    float part = 0.f, cnt = 0.f;
    for (int t = l; t < T_; t += 64) {
        int lt = lab[t];
        if (lt > -1) {
            cnt += 1.f;
            if (t > 0) part += tr[lab[t - 1] * 32 + lt] + eb[t * K_ + lt];
        }
    }
    #pragma unroll
    for (int o = 32; o; o >>= 1) { part += __shfl_xor(part, o); cnt += __shfl_xor(cnt, o); }
    int lastidx = (int)cnt - 1;
    float num = part + start[lab[0]] + eb[lab[0]] + endv[lab[lastidx]];

    float a = (l < K_) ? (start[l] + eb[l]) : -3.0e38f;
    for (int t = 1; t < T_; ++t) {
        if (l < K_) al[l] = a;
        __syncthreads();
        if (l < K_) {
            float m = -3.0e38f;
            #pragma unroll
            for (int i = 0; i < K_; ++i) m = fmaxf(m, al[i] + tr[i * 32 + l]);
            float ss = 0.f;
            #pragma unroll
            for (int i = 0; i < K_; ++i) ss += __expf(al[i] + tr[i * 32 + l] - m);
            float anew = eb[t * K_ + l] + m + __logf(ss);
            if (lab[t] > -1) a = anew;
        }
        __syncthreads();
    }
    float v = (l < K_) ? (a + endv[l]) : -3.0e38f;
    float m = v;
    #pragma unroll
    for (int o = 32; o; o >>= 1) m = fmaxf(m, __shfl_xor(m, o));
    float ss = (l < K_) ? __expf(v - m) : 0.f;
    #pragma unroll
    for (int o = 32; o; o >>= 1) ss += __shfl_xor(ss, o);
    if (l == 0) partials[b] = num - (m + __logf(ss));
}

__global__ __launch_bounds__(64) void loss_reduce(const float* __restrict__ partials,
                                                  float* __restrict__ out) {
    float v = partials[threadIdx.x];
    #pragma unroll
    for (int o = 32; o; o >>= 1) v += __shfl_xor(v, o);
    if (threadIdx.x == 0) out[0] = -v;
}

__global__ void sentinel(float* __restrict__ out, float v) { out[0] = -v; }

// ---------------- host ----------------
extern "C" void kernel_launch(void* const* d_in, const int* in_sizes, int n_in,
                              void* d_out, int out_size, void* d_ws, size_t ws_size,
                              hipStream_t stream) {
    const int*   ids      = (const int*)d_in[0];
    const int*   labels   = (const int*)d_in[1];
    const float* emb      = (const float*)d_in[2];
    const float* wih[4]   = { (const float*)d_in[3], (const float*)d_in[7], (const float*)d_in[11], (const float*)d_in[15] };
    const float* whh[4]   = { (const float*)d_in[4], (const float*)d_in[8], (const float*)d_in[12], (const float*)d_in[16] };
    const float* bih[4]   = { (const float*)d_in[5], (const float*)d_in[9], (const float*)d_in[13], (const float*)d_in[17] };
    const float* bhh[4]   = { (const float*)d_in[6], (const float*)d_in[10], (const float*)d_in[14], (const float*)d_in[18] };
    const float* cls_w    = (const float*)d_in[19];
    const float* cls_b    = (const float*)d_in[20];
    const float* c_start  = (const float*)d_in[21];
    const float* c_end    = (const float*)d_in[22];
    const float* c_trans  = (const float*)d_in[23];
    float* out = (float*)d_out;
    float* out1 = out + 1;

    char* p = (char*)d_ws;
    size_t used = 0;
    auto alloc = [&](size_t bytes) -> char* {
        char* r = p;
        size_t a = (bytes + 255) & ~(size_t)255;
        p += a; used += a;
        return r;
    };
    unsigned short* xpcf = (unsigned short*)alloc((size_t)B_ * TC_ * G_ * 2);   // 12.6MB
    unsigned short* xpcb = (unsigned short*)alloc((size_t)B_ * TC_ * G_ * 2);   // 12.6MB
    unsigned short* h1   = (unsigned short*)alloc((size_t)BT_ * H2_ * 2);       // 67MB
    unsigned short* xbf  = (unsigned short*)alloc((size_t)BT_ * E_ * 2);        // 16.8MB
    // layer-1 output chunks alias the (then-dead) embedding buffer
    unsigned short* gof  = xbf;
    unsigned short* gob  = xbf + (size_t)B_ * TC_ * H_;
    unsigned short* wihb[4];
    unsigned short* whhb[4];
    const int wihsz[4] = { G_ * E_, G_ * E_, G_ * H2_, G_ * H2_ };
    for (int i = 0; i < 4; ++i) {
        wihb[i] = (unsigned short*)alloc((size_t)wihsz[i] * 2);
        whhb[i] = (unsigned short*)alloc((size_t)G_ * H_ * 2);
    }
    unsigned short* clsf  = (unsigned short*)alloc((size_t)32 * H_ * 2);
    unsigned short* clshb = (unsigned short*)alloc((size_t)32 * H_ * 2);
    unsigned int*   hpub  = (unsigned int*)alloc((size_t)2 * 2 * B_ * (H_ / 2) * 4);  // 256KB
    float*          hcar  = (float*)alloc((size_t)2 * B_ * H_ * 4);                    // 256KB
    float*          partials = (float*)alloc((size_t)B_ * 4);
    int*            flags = (int*)alloc((size_t)2 * NC_ * 2048 * 4);            // [launch][dir*1024 + wk*32]

    if (used > ws_size) {
        sentinel<<<dim3(1), dim3(1), 0, stream>>>(out, (float)(ws_size >> 20));
        return;
    }

    hipMemsetAsync(flags, 0, (size_t)2 * NC_ * 2048 * 4, stream);

    auto cvt = [&](const float* s_, unsigned short* d_, int n) {
        int grid = (n + 255) / 256; if (grid > 2048) grid = 2048;
        cvt_f32_bf16<<<dim3(grid), dim3(256), 0, stream>>>(s_, d_, n);
    };
    for (int i = 0; i < 4; ++i) { cvt(wih[i], wihb[i], wihsz[i]); cvt(whh[i], whhb[i], G_ * H_); }
    cvt_cls<<<dim3((32 * H_ + 255) / 256), dim3(256), 0, stream>>>(cls_w, clsf, clshb);
    emis_bias_init<<<dim3(1024), dim3(256), 0, stream>>>(cls_b, out1);
    embed_gather<<<dim3(BT_ / 4), dim3(256), 0, stream>>>(ids, emb, xbf);

    for (int layer = 0; layer < 2; ++layer) {
        const unsigned short* Ain = layer ? h1 : xbf;
        const int lda  = layer ? H2_ : E_;
        const unsigned short* wf = wihb[layer * 2 + 0];
        const unsigned short* wb = wihb[layer * 2 + 1];
        const float* bf_ = bih[layer * 2 + 0];
        const float* bb_ = bih[layer * 2 + 1];
        const unsigned short* whf = whhb[layer * 2 + 0];
        const unsigned short* whb = whhb[layer * 2 + 1];
        const float* bhf = bhh[layer * 2 + 0];
        const float* bhb = bhh[layer * 2 + 1];

        for (int c = 0; c < NC_; ++c) {
            int t0f = c * TC_;
            int t0b = T_ - (c + 1) * TC_;
            // xp for this chunk (bias folded, bf16 out)
            gemm_bf16<false, false><<<dim3(B_, G_ / 64), dim3(256), 0, stream>>>(
                Ain, lda, t0f, T_, wf, lda, G_, bf_, (void*)xpcf, G_, 0, TC_, G_, lda);
            gemm_bf16<false, false><<<dim3(B_, G_ / 64), dim3(256), 0, stream>>>(
                Ain, lda, t0b, T_, wb, lda, G_, bb_, (void*)xpcb, G_, 0, TC_, G_, lda);
            // persistent scan over the chunk (grid 64, fence-free)
            int* fl2 = flags + (layer * NC_ + c) * 2048;
            if (layer == 0) {
                gru_scan<<<dim3(64), dim3(256), 0, stream>>>(c, xpcf, xpcb,
                    whf, whb, bhf, bhb, hpub, hcar, h1, h1 + H_, H2_, 0, fl2);
            } else {
                gru_scan<<<dim3(64), dim3(256), 0, stream>>>(c, xpcf, xpcb,
                    whf, whb, bhf, bhb, hpub, hcar, gof, gob, H_, 1, fl2);
            }
            if (layer == 1) {
                // split-K emissions for the fresh rows of this chunk (+= into out1)
                gemm_bf16<true, true><<<dim3(B_, 1), dim3(256), 0, stream>>>(
                    gof, H_, 0, TC_, clsf, H_, 32, nullptr, (void*)out1, K_, t0f, T_, K_, H_);
                gemm_bf16<true, true><<<dim3(B_, 1), dim3(256), 0, stream>>>(
                    gob, H_, 0, TC_, clshb, H_, 32, nullptr, (void*)out1, K_, t0b, T_, K_, H_);
            }
        }
    }

    crf_kernel<<<dim3(B_), dim3(64), 0, stream>>>(out1, labels, c_start, c_end, c_trans, partials);
    loss_reduce<<<dim3(1), dim3(64), 0, stream>>>(partials, out);
}